// Round 1
// baseline (976.977 us; speedup 1.0000x reference)
//
#include <hip/hip_runtime.h>
#include <hip/hip_bf16.h>
#include <stdint.h>

#define KP   10048   // padded D_IN: 314*32
#define DIN  10000
#define NB   8192
#define HID  1024
#define EMB  128

typedef __attribute__((ext_vector_type(8))) __bf16 bf16x8;
typedef __attribute__((ext_vector_type(4))) float  f32x4;
typedef __attribute__((ext_vector_type(8))) unsigned short ushort8;

typedef const __attribute__((address_space(1))) void* gas_cp;
typedef __attribute__((address_space(3))) void* las_p;

__device__ __forceinline__ unsigned short f2bf(float f) {
    union { float f; unsigned u; } c; c.f = f;
    unsigned u = c.u;
    u += 0x7FFFu + ((u >> 16) & 1u);   // round-to-nearest-even
    return (unsigned short)(u >> 16);
}

// ---- fp32 [rows][DIN] -> bf16 [rows][KP], zero-padded cols [DIN,KP) ----
__global__ void conv_pad(const float* __restrict__ src, unsigned short* __restrict__ dst,
                         int rows) {
    const int cpr = KP / 8;    // 1256 chunks per dst row
    const int scr = DIN / 8;   // 1250 chunks with real data
    long total = (long)rows * cpr;
    long stride = (long)gridDim.x * blockDim.x;
    for (long c = (long)blockIdx.x * blockDim.x + threadIdx.x; c < total; c += stride) {
        int row = (int)(c / cpr);
        int cc  = (int)(c % cpr);
        ushort8 o;
        if (cc < scr) {
            const float4* s = (const float4*)(src + (size_t)row * DIN + (size_t)cc * 8);
            float4 a = s[0], b = s[1];
            o[0] = f2bf(a.x); o[1] = f2bf(a.y); o[2] = f2bf(a.z); o[3] = f2bf(a.w);
            o[4] = f2bf(b.x); o[5] = f2bf(b.y); o[6] = f2bf(b.z); o[7] = f2bf(b.w);
        } else {
#pragma unroll
            for (int j = 0; j < 8; ++j) o[j] = 0;
        }
        *(ushort8*)(dst + (size_t)row * KP + (size_t)cc * 8) = o;
    }
}

// ---- fp32 src[K][N] -> bf16 dst[N][Kp] (transpose), zero-pad k in [K,Kp) ----
__global__ void conv_transpose(const float* __restrict__ src, unsigned short* __restrict__ dst,
                               int K, int N, int Kp) {
    const int cpr = Kp / 8;
    long total = (long)N * cpr;
    long stride = (long)gridDim.x * blockDim.x;
    for (long c = (long)blockIdx.x * blockDim.x + threadIdx.x; c < total; c += stride) {
        int n  = (int)(c / cpr);
        int k0 = (int)(c % cpr) * 8;
        ushort8 o;
        if (k0 < K) {
#pragma unroll
            for (int j = 0; j < 8; ++j) o[j] = f2bf(src[(size_t)(k0 + j) * N + n]);
        } else {
#pragma unroll
            for (int j = 0; j < 8; ++j) o[j] = 0;
        }
        *(ushort8*)(dst + (size_t)n * Kp + k0) = o;
    }
}

// ---- C = act(A @ B^T + bias):  A[M][lda] bf16 row-major, Bt[N][ldb] bf16 (B transposed)
// m97 structure: 128x128 tile, BK=32, 4 waves (2x2), global_load_lds staging,
// 16x16x32 bf16 MFMA, acc 4x4 fragments per wave.
template<bool RELU, bool OUTBF16>
__global__ __launch_bounds__(256, 2)
void gemm_rt_bt(const unsigned short* __restrict__ A,
                const unsigned short* __restrict__ Bt,
                const float* __restrict__ bias,
                void* __restrict__ Cout,
                int lda, int ldb, int ldc, int nk) {
    __shared__ unsigned short As[128 * 32];
    __shared__ unsigned short Bs[128 * 32];

    const int t    = threadIdx.x;
    const int lane = t & 63;
    const int wave = t >> 6;
    const int wr   = wave >> 1, wc = wave & 1;
    const int rA   = lane & 15;
    const int kg   = lane >> 4;

    const int bm = blockIdx.y, bn = blockIdx.x;

    // staging: pass p (p=0,1) covers rows p*64 + (t>>2), cols (t&3)*8 .. +8
    const unsigned short* ga = A  + (size_t)(bm * 128 + (t >> 2)) * lda + (size_t)(t & 3) * 8;
    const unsigned short* gb = Bt + (size_t)(bn * 128 + (t >> 2)) * ldb + (size_t)(t & 3) * 8;
    const size_t aP = (size_t)64 * lda;   // pass-1 row offset
    const size_t bP = (size_t)64 * ldb;

    unsigned short* lA = As + wave * 512; // wave-uniform LDS base (elements)
    unsigned short* lB = Bs + wave * 512;

    f32x4 acc[4][4] = {};

    const int aoff = (wr * 64 + rA) * 32 + kg * 8;  // element offsets into LDS
    const int boff = (wc * 64 + rA) * 32 + kg * 8;

    for (int kt = 0; kt < nk; ++kt) {
        __builtin_amdgcn_global_load_lds((gas_cp)(ga),      (las_p)(lA),        16, 0, 0);
        __builtin_amdgcn_global_load_lds((gas_cp)(ga + aP), (las_p)(lA + 2048), 16, 0, 0);
        __builtin_amdgcn_global_load_lds((gas_cp)(gb),      (las_p)(lB),        16, 0, 0);
        __builtin_amdgcn_global_load_lds((gas_cp)(gb + bP), (las_p)(lB + 2048), 16, 0, 0);
        ga += 32; gb += 32;
        __syncthreads();   // drains vmcnt + barrier

        bf16x8 af[4], bfr[4];
#pragma unroll
        for (int m = 0; m < 4; ++m) af[m]  = *(const bf16x8*)(As + aoff + m * 16 * 32);
#pragma unroll
        for (int n = 0; n < 4; ++n) bfr[n] = *(const bf16x8*)(Bs + boff + n * 16 * 32);
#pragma unroll
        for (int m = 0; m < 4; ++m)
#pragma unroll
            for (int n = 0; n < 4; ++n)
                acc[m][n] = __builtin_amdgcn_mfma_f32_16x16x32_bf16(af[m], bfr[n], acc[m][n], 0, 0, 0);
        __syncthreads();   // protect LDS before next stage
    }

    // epilogue: C/D layout col=lane&15, row=(lane>>4)*4+reg
    const int rowbase = bm * 128 + wr * 64 + kg * 4;
    const int colbase = bn * 128 + wc * 64 + rA;
#pragma unroll
    for (int n = 0; n < 4; ++n) {
        const int col = colbase + n * 16;
        const float bv = bias[col];
#pragma unroll
        for (int m = 0; m < 4; ++m) {
#pragma unroll
            for (int r = 0; r < 4; ++r) {
                float v = acc[m][n][r] + bv;
                if (RELU) v = fmaxf(v, 0.0f);
                const int row = rowbase + m * 16 + r;
                if (OUTBF16)
                    ((unsigned short*)Cout)[(size_t)row * ldc + col] = f2bf(v);
                else
                    ((float*)Cout)[(size_t)row * ldc + col] = v;
            }
        }
    }
}

// ---- out[i] = sum_e P[i][e] * Q[i][e]  (one wave per row, E=128 -> float2/lane) ----
__global__ void rowdot(const float* __restrict__ P, const float* __restrict__ Q,
                       float* __restrict__ out, int n) {
    int gid = blockIdx.x * blockDim.x + threadIdx.x;
    int w = gid >> 6, lane = gid & 63;
    if (w >= n) return;
    const float2 p = ((const float2*)(P + (size_t)w * EMB))[lane];
    const float2 q = ((const float2*)(Q + (size_t)w * EMB))[lane];
    float s = p.x * q.x + p.y * q.y;
#pragma unroll
    for (int off = 32; off; off >>= 1) s += __shfl_down(s, off);
    if (lane == 0) out[w] = s;
}

extern "C" void kernel_launch(void* const* d_in, const int* in_sizes, int n_in,
                              void* d_out, int out_size, void* d_ws, size_t ws_size,
                              hipStream_t stream) {
    const float* user = (const float*)d_in[0];
    const float* item = (const float*)d_in[1];
    const float* Wu1  = (const float*)d_in[2];
    const float* bu1  = (const float*)d_in[3];
    const float* Wu2  = (const float*)d_in[4];
    const float* bu2  = (const float*)d_in[5];
    const float* Wi1  = (const float*)d_in[6];
    const float* bi1  = (const float*)d_in[7];
    const float* Wi2  = (const float*)d_in[8];
    const float* bi2  = (const float*)d_in[9];
    float* out = (float*)d_out;

    char* ws = (char*)d_ws;
    size_t off = 0;
    auto alloc = [&](size_t bytes) {
        char* p = ws + off;
        off += (bytes + 255) & ~(size_t)255;
        return p;
    };

    unsigned short* W1t = (unsigned short*)alloc((size_t)HID * KP * 2);  // [1024][10048]
    unsigned short* W2t = (unsigned short*)alloc((size_t)EMB * HID * 2); // [128][1024]
    float* P = (float*)alloc((size_t)NB * EMB * 4);
    float* Q = (float*)alloc((size_t)NB * EMB * 4);

    // A-chunk + H1-chunk sized from remaining workspace (deterministic in ws_size)
    size_t rem = (ws_size > off) ? (ws_size - off) : 0;
    const size_t perRow = (size_t)KP * 2 + (size_t)HID * 2;  // 22144 B / batch row
    int mc = (int)(rem / perRow);
    mc = (mc / 128) * 128;
    if (mc > NB) mc = NB;
    if (mc < 128) mc = 128;  // minimum viable; ws smaller than ~28MB cannot work anyway
    unsigned short* Abf = (unsigned short*)alloc((size_t)mc * KP * 2);
    unsigned short* H1  = (unsigned short*)alloc((size_t)mc * HID * 2);

    dim3 blk(256);
    for (int side = 0; side < 2; ++side) {
        const float* X  = side ? item : user;
        const float* W1 = side ? Wi1 : Wu1;
        const float* b1 = side ? bi1 : bu1;
        const float* W2 = side ? Wi2 : Wu2;
        const float* b2 = side ? bi2 : bu2;
        float* PQ = side ? Q : P;

        conv_transpose<<<2048, blk, 0, stream>>>(W1, W1t, DIN, HID, KP);
        conv_transpose<<<64,   blk, 0, stream>>>(W2, W2t, HID, EMB, HID);

        for (int m0 = 0; m0 < NB; m0 += mc) {
            int rows = (mc < NB - m0) ? mc : (NB - m0);
            conv_pad<<<2048, blk, 0, stream>>>(X + (size_t)m0 * DIN, Abf, rows);
            dim3 g1(HID / 128, rows / 128);
            gemm_rt_bt<true, true><<<g1, blk, 0, stream>>>(
                Abf, W1t, b1, H1, KP, KP, HID, KP / 32);
            dim3 g2(EMB / 128, rows / 128);
            gemm_rt_bt<false, false><<<g2, blk, 0, stream>>>(
                H1, W2t, b2, PQ + (size_t)m0 * EMB, HID, HID, EMB, HID / 32);
        }
    }
    rowdot<<<(NB * 64) / 256, blk, 0, stream>>>(P, Q, out, NB);
}

// Round 2
// 827.528 us; speedup vs baseline: 1.1806x; 1.1806x over previous
//
#include <hip/hip_runtime.h>
#include <hip/hip_bf16.h>
#include <stdint.h>

#define KP   10048   // padded D_IN: 314*32
#define DIN  10000
#define NB   8192
#define HID  1024
#define EMB  128

typedef __attribute__((ext_vector_type(8))) __bf16 bf16x8;
typedef __attribute__((ext_vector_type(4))) float  f32x4;
typedef __attribute__((ext_vector_type(8))) unsigned short ushort8;

typedef const __attribute__((address_space(1))) void* gas_cp;
typedef __attribute__((address_space(3))) void* las_p;

__device__ __forceinline__ unsigned short f2bf(float f) {
    union { float f; unsigned u; } c; c.f = f;
    unsigned u = c.u;
    u += 0x7FFFu + ((u >> 16) & 1u);   // round-to-nearest-even
    return (unsigned short)(u >> 16);
}

// ---- fp32 [rows][DIN] -> bf16 [rows][KP], zero-padded cols [DIN,KP) ----
__global__ void conv_pad(const float* __restrict__ src, unsigned short* __restrict__ dst,
                         int rows) {
    const int cpr = KP / 8;    // 1256 chunks per dst row
    const int scr = DIN / 8;   // 1250 chunks with real data
    long total = (long)rows * cpr;
    long stride = (long)gridDim.x * blockDim.x;
    for (long c = (long)blockIdx.x * blockDim.x + threadIdx.x; c < total; c += stride) {
        int row = (int)(c / cpr);
        int cc  = (int)(c % cpr);
        ushort8 o;
        if (cc < scr) {
            const float4* s = (const float4*)(src + (size_t)row * DIN + (size_t)cc * 8);
            float4 a = s[0], b = s[1];
            o[0] = f2bf(a.x); o[1] = f2bf(a.y); o[2] = f2bf(a.z); o[3] = f2bf(a.w);
            o[4] = f2bf(b.x); o[5] = f2bf(b.y); o[6] = f2bf(b.z); o[7] = f2bf(b.w);
        } else {
#pragma unroll
            for (int j = 0; j < 8; ++j) o[j] = 0;
        }
        *(ushort8*)(dst + (size_t)row * KP + (size_t)cc * 8) = o;
    }
}

// ---- fp32 src[K][N] -> bf16 dst[N][Kp] via LDS tile transpose (coalesced both sides)
// tile: 64 k-rows x 32 n-cols, block 256 = (32,8) logical
__global__ void conv_transpose(const float* __restrict__ src, unsigned short* __restrict__ dst,
                               int K, int N, int Kp) {
    __shared__ float tile[64][33];
    const int tx = threadIdx.x & 31, ty = threadIdx.x >> 5;
    const int k0 = blockIdx.x * 64, n0 = blockIdx.y * 32;
#pragma unroll
    for (int j = 0; j < 8; ++j) {
        int k = k0 + ty + j * 8;
        tile[ty + j * 8][tx] = (k < K) ? src[(size_t)k * N + n0 + tx] : 0.0f;
    }
    __syncthreads();
#pragma unroll
    for (int j = 0; j < 4; ++j) {
        int n = n0 + ty + j * 8;
        unsigned short lo = f2bf(tile[2 * tx][ty + j * 8]);
        unsigned short hi = f2bf(tile[2 * tx + 1][ty + j * 8]);
        unsigned int packed = (unsigned int)lo | ((unsigned int)hi << 16);
        *(unsigned int*)(dst + (size_t)n * Kp + k0 + 2 * tx) = packed;
    }
}

// ---- C = act(A @ B^T + bias):  A[M][lda] bf16 row-major, Bt[N][ldb] bf16
// 128x128 tile, BK=32, 4 waves (2x2), double-buffered global_load_lds prefetch
// (issue next tile BEFORE compute; single barrier-drain per K-step = T3-min 2-phase),
// 16x16x32 bf16 MFMA, acc 4x4 fragments per wave.
// SWZ: bijective XCD remap assuming gridDim.x == 8 (so each XCD owns a contiguous
// band of 8 A-row-panels x all B-cols -> per-XCD unique working set 41 MB not 167 MB).
template<bool RELU, bool OUTBF16, bool SWZ>
__global__ __launch_bounds__(256, 2)
void gemm_rt_bt(const unsigned short* __restrict__ A,
                const unsigned short* __restrict__ Bt,
                const float* __restrict__ bias,
                void* __restrict__ Cout,
                int lda, int ldb, int ldc, int nk) {
    __shared__ unsigned short As[2 * 4096];
    __shared__ unsigned short Bs[2 * 4096];

    const int t    = threadIdx.x;
    const int lane = t & 63;
    const int wave = t >> 6;
    const int wr   = wave >> 1, wc = wave & 1;
    const int rA   = lane & 15;
    const int kg   = lane >> 4;

    int bm, bn;
    if (SWZ) {
        // raw dispatch id; id%8 ~ XCD. Give XCD x the contiguous pos-range
        // [x*chunk, (x+1)*chunk). pos enumerated bm-major with gridDim.x==8.
        const int id    = blockIdx.y * gridDim.x + blockIdx.x;
        const int chunk = (gridDim.x * gridDim.y) >> 3;
        const int pos   = (id & 7) * chunk + (id >> 3);
        bm = pos >> 3;         // gridDim.x == 8
        bn = pos & 7;
    } else {
        bm = blockIdx.y; bn = blockIdx.x;
    }

    // staging: pass p (p=0,1) covers rows p*64 + (t>>2), cols (t&3)*8 .. +8
    const unsigned short* ga = A  + (size_t)(bm * 128 + (t >> 2)) * lda + (size_t)(t & 3) * 8;
    const unsigned short* gb = Bt + (size_t)(bn * 128 + (t >> 2)) * ldb + (size_t)(t & 3) * 8;
    const size_t aP = (size_t)64 * lda;
    const size_t bP = (size_t)64 * ldb;

    f32x4 acc[4][4] = {};

    const int aoff = (wr * 64 + rA) * 32 + kg * 8;
    const int boff = (wc * 64 + rA) * 32 + kg * 8;
    const int wst  = wave * 512;   // wave-uniform stage base (elements)

    // ---- prologue: stage tile 0 into buffer 0 ----
    __builtin_amdgcn_global_load_lds((gas_cp)(ga),      (las_p)(As + wst),        16, 0, 0);
    __builtin_amdgcn_global_load_lds((gas_cp)(ga + aP), (las_p)(As + wst + 2048), 16, 0, 0);
    __builtin_amdgcn_global_load_lds((gas_cp)(gb),      (las_p)(Bs + wst),        16, 0, 0);
    __builtin_amdgcn_global_load_lds((gas_cp)(gb + bP), (las_p)(Bs + wst + 2048), 16, 0, 0);
    ga += 32; gb += 32;
    __syncthreads();   // drain vmcnt + barrier: buffer 0 ready

    const int nk1 = nk - 1;
    for (int kt = 0; kt < nk1; ++kt) {
        const int cb = (kt & 1) << 12;        // current buffer (elements)
        const int pb = cb ^ 4096;             // prefetch buffer

        // issue next tile's loads FIRST (latency overlaps the compute below)
        __builtin_amdgcn_global_load_lds((gas_cp)(ga),      (las_p)(As + pb + wst),        16, 0, 0);
        __builtin_amdgcn_global_load_lds((gas_cp)(ga + aP), (las_p)(As + pb + wst + 2048), 16, 0, 0);
        __builtin_amdgcn_global_load_lds((gas_cp)(gb),      (las_p)(Bs + pb + wst),        16, 0, 0);
        __builtin_amdgcn_global_load_lds((gas_cp)(gb + bP), (las_p)(Bs + pb + wst + 2048), 16, 0, 0);
        ga += 32; gb += 32;

        bf16x8 af[4], bfr[4];
#pragma unroll
        for (int m = 0; m < 4; ++m) af[m]  = *(const bf16x8*)(As + cb + aoff + m * 512);
#pragma unroll
        for (int n = 0; n < 4; ++n) bfr[n] = *(const bf16x8*)(Bs + cb + boff + n * 512);
#pragma unroll
        for (int m = 0; m < 4; ++m)
#pragma unroll
            for (int n = 0; n < 4; ++n)
                acc[m][n] = __builtin_amdgcn_mfma_f32_16x16x32_bf16(af[m], bfr[n], acc[m][n], 0, 0, 0);

        __syncthreads();   // drains prefetch vmcnt (residual after compute) + barrier
    }

    // ---- last tile ----
    {
        const int cb = (nk1 & 1) << 12;
        bf16x8 af[4], bfr[4];
#pragma unroll
        for (int m = 0; m < 4; ++m) af[m]  = *(const bf16x8*)(As + cb + aoff + m * 512);
#pragma unroll
        for (int n = 0; n < 4; ++n) bfr[n] = *(const bf16x8*)(Bs + cb + boff + n * 512);
#pragma unroll
        for (int m = 0; m < 4; ++m)
#pragma unroll
            for (int n = 0; n < 4; ++n)
                acc[m][n] = __builtin_amdgcn_mfma_f32_16x16x32_bf16(af[m], bfr[n], acc[m][n], 0, 0, 0);
    }

    // epilogue: C/D layout col=lane&15, row=(lane>>4)*4+reg
    const int rowbase = bm * 128 + wr * 64 + kg * 4;
    const int colbase = bn * 128 + wc * 64 + rA;
#pragma unroll
    for (int n = 0; n < 4; ++n) {
        const int col = colbase + n * 16;
        const float bv = bias[col];
#pragma unroll
        for (int m = 0; m < 4; ++m) {
#pragma unroll
            for (int r = 0; r < 4; ++r) {
                float v = acc[m][n][r] + bv;
                if (RELU) v = fmaxf(v, 0.0f);
                const int row = rowbase + m * 16 + r;
                if (OUTBF16)
                    ((unsigned short*)Cout)[(size_t)row * ldc + col] = f2bf(v);
                else
                    ((float*)Cout)[(size_t)row * ldc + col] = v;
            }
        }
    }
}

// ---- out[i] = sum_e P[i][e] * Q[i][e]  (one wave per row, E=128 -> float2/lane) ----
__global__ void rowdot(const float* __restrict__ P, const float* __restrict__ Q,
                       float* __restrict__ out, int n) {
    int gid = blockIdx.x * blockDim.x + threadIdx.x;
    int w = gid >> 6, lane = gid & 63;
    if (w >= n) return;
    const float2 p = ((const float2*)(P + (size_t)w * EMB))[lane];
    const float2 q = ((const float2*)(Q + (size_t)w * EMB))[lane];
    float s = p.x * q.x + p.y * q.y;
#pragma unroll
    for (int off = 32; off; off >>= 1) s += __shfl_down(s, off);
    if (lane == 0) out[w] = s;
}

extern "C" void kernel_launch(void* const* d_in, const int* in_sizes, int n_in,
                              void* d_out, int out_size, void* d_ws, size_t ws_size,
                              hipStream_t stream) {
    const float* user = (const float*)d_in[0];
    const float* item = (const float*)d_in[1];
    const float* Wu1  = (const float*)d_in[2];
    const float* bu1  = (const float*)d_in[3];
    const float* Wu2  = (const float*)d_in[4];
    const float* bu2  = (const float*)d_in[5];
    const float* Wi1  = (const float*)d_in[6];
    const float* bi1  = (const float*)d_in[7];
    const float* Wi2  = (const float*)d_in[8];
    const float* bi2  = (const float*)d_in[9];
    float* out = (float*)d_out;

    char* ws = (char*)d_ws;
    size_t off = 0;
    auto alloc = [&](size_t bytes) {
        char* p = ws + off;
        off += (bytes + 255) & ~(size_t)255;
        return p;
    };

    unsigned short* W1t = (unsigned short*)alloc((size_t)HID * KP * 2);  // [1024][10048]
    unsigned short* W2t = (unsigned short*)alloc((size_t)EMB * HID * 2); // [128][1024]
    float* P = (float*)alloc((size_t)NB * EMB * 4);
    float* Q = (float*)alloc((size_t)NB * EMB * 4);

    size_t rem = (ws_size > off) ? (ws_size - off) : 0;
    const size_t perRow = (size_t)KP * 2 + (size_t)HID * 2;  // 22144 B / batch row
    int mc = (int)(rem / perRow);
    mc = (mc / 128) * 128;
    if (mc > NB) mc = NB;
    if (mc < 128) mc = 128;
    unsigned short* Abf = (unsigned short*)alloc((size_t)mc * KP * 2);
    unsigned short* H1  = (unsigned short*)alloc((size_t)mc * HID * 2);

    dim3 blk(256);
    for (int side = 0; side < 2; ++side) {
        const float* X  = side ? item : user;
        const float* W1 = side ? Wi1 : Wu1;
        const float* b1 = side ? bi1 : bu1;
        const float* W2 = side ? Wi2 : Wu2;
        const float* b2 = side ? bi2 : bu2;
        float* PQ = side ? Q : P;

        conv_transpose<<<dim3(KP / 64, HID / 32), blk, 0, stream>>>(W1, W1t, DIN, HID, KP);
        conv_transpose<<<dim3(HID / 64, EMB / 32), blk, 0, stream>>>(W2, W2t, HID, EMB, HID);

        for (int m0 = 0; m0 < NB; m0 += mc) {
            int rows = (mc < NB - m0) ? mc : (NB - m0);
            conv_pad<<<2048, blk, 0, stream>>>(X + (size_t)m0 * DIN, Abf, rows);
            dim3 g1(HID / 128, rows / 128);
            gemm_rt_bt<true, true, true><<<g1, blk, 0, stream>>>(
                Abf, W1t, b1, H1, KP, KP, HID, KP / 32);
            dim3 g2(EMB / 128, rows / 128);
            gemm_rt_bt<false, false, false><<<g2, blk, 0, stream>>>(
                H1, W2t, b2, PQ + (size_t)m0 * EMB, HID, HID, EMB, HID / 32);
        }
    }
    rowdot<<<(NB * 64) / 256, blk, 0, stream>>>(P, Q, out, NB);
}

// Round 3
// 782.296 us; speedup vs baseline: 1.2489x; 1.0578x over previous
//
#include <hip/hip_runtime.h>
#include <hip/hip_bf16.h>
#include <stdint.h>

#define KP   10048   // padded D_IN: 314*32
#define DIN  10000
#define NB   8192
#define HID  1024
#define EMB  128

typedef __attribute__((ext_vector_type(8))) __bf16 bf16x8;
typedef __attribute__((ext_vector_type(4))) float  f32x4;
typedef __attribute__((ext_vector_type(8))) unsigned short ushort8;
typedef __attribute__((ext_vector_type(4))) unsigned short ushort4v;

typedef const __attribute__((address_space(1))) void* gas_cp;
typedef __attribute__((address_space(3))) void* las_p;

__device__ __forceinline__ unsigned short f2bf(float f) {
    union { float f; unsigned u; } c; c.f = f;
    unsigned u = c.u;
    u += 0x7FFFu + ((u >> 16) & 1u);   // round-to-nearest-even
    return (unsigned short)(u >> 16);
}

// ---- fp32 [rows][DIN] -> bf16 [rows][KP]; thread = one float4 chunk (unit-stride) ----
__global__ void conv_pad(const float* __restrict__ src, unsigned short* __restrict__ dst) {
    const int c4  = blockIdx.x * blockDim.x + threadIdx.x;  // float4-chunk within row
    const int row = blockIdx.y;
    const int cpr = KP / 4;   // 2512
    if (c4 >= cpr) return;
    ushort4v o;
    if (c4 < DIN / 4) {
        float4 a = *(const float4*)(src + (size_t)row * DIN + (size_t)c4 * 4);
        o[0] = f2bf(a.x); o[1] = f2bf(a.y); o[2] = f2bf(a.z); o[3] = f2bf(a.w);
    } else {
        o[0] = o[1] = o[2] = o[3] = 0;
    }
    *(ushort4v*)(dst + (size_t)row * KP + (size_t)c4 * 4) = o;
}

// ---- fp32 src[K][N] -> bf16 dst[N][Kp] via LDS tile transpose ----
__global__ void conv_transpose(const float* __restrict__ src, unsigned short* __restrict__ dst,
                               int K, int N, int Kp) {
    __shared__ float tile[64][33];
    const int tx = threadIdx.x & 31, ty = threadIdx.x >> 5;
    const int k0 = blockIdx.x * 64, n0 = blockIdx.y * 32;
#pragma unroll
    for (int j = 0; j < 8; ++j) {
        int k = k0 + ty + j * 8;
        tile[ty + j * 8][tx] = (k < K) ? src[(size_t)k * N + n0 + tx] : 0.0f;
    }
    __syncthreads();
#pragma unroll
    for (int j = 0; j < 4; ++j) {
        int n = n0 + ty + j * 8;
        unsigned short lo = f2bf(tile[2 * tx][ty + j * 8]);
        unsigned short hi = f2bf(tile[2 * tx + 1][ty + j * 8]);
        unsigned int packed = (unsigned int)lo | ((unsigned int)hi << 16);
        *(unsigned int*)(dst + (size_t)n * Kp + k0 + 2 * tx) = packed;
    }
}

// ---- C = act(A @ B^T + bias), 128x128 tile, BK=32, 4 waves (2x2) ----
// 3-buffer pipeline with counted vmcnt (T4): loads for tile kt+2 issued while
// computing tile kt; s_waitcnt vmcnt(8) keeps 2 tiles in flight across raw
// s_barriers (never drain to 0 in the main loop). Last 2 iterations peeled
// (vmcnt(4), vmcnt(0)).
// LDS XOR-swizzle (T2, both-sides): source col-chunk pre-swizzled with
// (row>>1)&3 so gload_lds's linear write lands swizzled; read XORs kg the
// same way -> 16 lanes/kg-group spread over 8 distinct 16B slots (2-way, free).
template<bool RELU, bool OUTBF16, bool SWZ>
__global__ __launch_bounds__(256, 2)
void gemm_rt_bt(const unsigned short* __restrict__ A,
                const unsigned short* __restrict__ Bt,
                const float* __restrict__ bias,
                void* __restrict__ Cout,
                int lda, int ldb, int ldc, int nk) {
    __shared__ unsigned short As[3 * 4096];
    __shared__ unsigned short Bs[3 * 4096];

    const int t    = threadIdx.x;
    const int lane = t & 63;
    const int wave = t >> 6;
    const int wr   = wave >> 1, wc = wave & 1;
    const int rA   = lane & 15;
    const int kg   = lane >> 4;

    int bm, bn;
    if (SWZ) {
        const int id    = blockIdx.y * gridDim.x + blockIdx.x;
        const int chunk = (gridDim.x * gridDim.y) >> 3;
        const int pos   = (id & 7) * chunk + (id >> 3);
        bm = pos >> 3;         // gridDim.x == 8
        bn = pos & 7;
    } else {
        bm = blockIdx.y; bn = blockIdx.x;
    }

    // staging: lane t covers row t>>2 (+64 for pass 1), source col-chunk XOR-swizzled
    const int srcc = (t & 3) ^ ((t >> 3) & 3);
    const unsigned short* ga = A  + (size_t)(bm * 128 + (t >> 2)) * lda + (size_t)srcc * 8;
    const unsigned short* gb = Bt + (size_t)(bn * 128 + (t >> 2)) * ldb + (size_t)srcc * 8;
    const size_t aP = (size_t)64 * lda;
    const size_t bP = (size_t)64 * ldb;

    f32x4 acc[4][4] = {};

    const int swz  = (rA >> 1) & 3;
    const int aoff = (wr * 64 + rA) * 32 + (kg ^ swz) * 8;
    const int boff = (wc * 64 + rA) * 32 + (kg ^ swz) * 8;
    const int wst  = wave * 512;   // wave-uniform stage base (elements)

    auto stage = [&](int buf) {
        const int bo = buf << 12;
        __builtin_amdgcn_global_load_lds((gas_cp)(ga),      (las_p)(As + bo + wst),        16, 0, 0);
        __builtin_amdgcn_global_load_lds((gas_cp)(ga + aP), (las_p)(As + bo + wst + 2048), 16, 0, 0);
        __builtin_amdgcn_global_load_lds((gas_cp)(gb),      (las_p)(Bs + bo + wst),        16, 0, 0);
        __builtin_amdgcn_global_load_lds((gas_cp)(gb + bP), (las_p)(Bs + bo + wst + 2048), 16, 0, 0);
        ga += 32; gb += 32;
    };
    auto compute = [&](int buf) {
        const int bo = buf << 12;
        bf16x8 af[4], bfr[4];
#pragma unroll
        for (int m = 0; m < 4; ++m) af[m]  = *(const bf16x8*)(As + bo + aoff + m * 512);
#pragma unroll
        for (int n = 0; n < 4; ++n) bfr[n] = *(const bf16x8*)(Bs + bo + boff + n * 512);
#pragma unroll
        for (int m = 0; m < 4; ++m)
#pragma unroll
            for (int n = 0; n < 4; ++n)
                acc[m][n] = __builtin_amdgcn_mfma_f32_16x16x32_bf16(af[m], bfr[n], acc[m][n], 0, 0, 0);
    };

    // prologue: tiles 0 and 1 in flight
    stage(0); stage(1);

    int cur = 0;
    for (int kt = 0; kt < nk - 2; ++kt) {
        int pfb = cur + 2; if (pfb >= 3) pfb -= 3;
        stage(pfb);                                     // tile kt+2 -> in flight
        asm volatile("s_waitcnt vmcnt(8)" ::: "memory"); // tile kt landed (2 in flight)
        __builtin_amdgcn_s_barrier();
        compute(cur);
        __builtin_amdgcn_s_barrier();                   // all reads of buf[cur] done
        cur = (cur + 1 == 3) ? 0 : cur + 1;
    }
    // kt = nk-2: only tile nk-1's 4 loads may remain outstanding
    asm volatile("s_waitcnt vmcnt(4)" ::: "memory");
    __builtin_amdgcn_s_barrier();
    compute(cur);
    cur = (cur + 1 == 3) ? 0 : cur + 1;
    // kt = nk-1
    asm volatile("s_waitcnt vmcnt(0)" ::: "memory");
    __builtin_amdgcn_s_barrier();
    compute(cur);

    // epilogue: C/D layout col=lane&15, row=(lane>>4)*4+reg
    const int rowbase = bm * 128 + wr * 64 + kg * 4;
    const int colbase = bn * 128 + wc * 64 + rA;
#pragma unroll
    for (int n = 0; n < 4; ++n) {
        const int col = colbase + n * 16;
        const float bv = bias[col];
#pragma unroll
        for (int m = 0; m < 4; ++m) {
#pragma unroll
            for (int r = 0; r < 4; ++r) {
                float v = acc[m][n][r] + bv;
                if (RELU) v = fmaxf(v, 0.0f);
                const int row = rowbase + m * 16 + r;
                if (OUTBF16)
                    ((unsigned short*)Cout)[(size_t)row * ldc + col] = f2bf(v);
                else
                    ((float*)Cout)[(size_t)row * ldc + col] = v;
            }
        }
    }
}

// ---- out[i] = sum_e P[i][e] * Q[i][e] ----
__global__ void rowdot(const float* __restrict__ P, const float* __restrict__ Q,
                       float* __restrict__ out, int n) {
    int gid = blockIdx.x * blockDim.x + threadIdx.x;
    int w = gid >> 6, lane = gid & 63;
    if (w >= n) return;
    const float2 p = ((const float2*)(P + (size_t)w * EMB))[lane];
    const float2 q = ((const float2*)(Q + (size_t)w * EMB))[lane];
    float s = p.x * q.x + p.y * q.y;
#pragma unroll
    for (int off = 32; off; off >>= 1) s += __shfl_down(s, off);
    if (lane == 0) out[w] = s;
}

extern "C" void kernel_launch(void* const* d_in, const int* in_sizes, int n_in,
                              void* d_out, int out_size, void* d_ws, size_t ws_size,
                              hipStream_t stream) {
    const float* user = (const float*)d_in[0];
    const float* item = (const float*)d_in[1];
    const float* Wu1  = (const float*)d_in[2];
    const float* bu1  = (const float*)d_in[3];
    const float* Wu2  = (const float*)d_in[4];
    const float* bu2  = (const float*)d_in[5];
    const float* Wi1  = (const float*)d_in[6];
    const float* bi1  = (const float*)d_in[7];
    const float* Wi2  = (const float*)d_in[8];
    const float* bi2  = (const float*)d_in[9];
    float* out = (float*)d_out;

    char* ws = (char*)d_ws;
    size_t off = 0;
    auto alloc = [&](size_t bytes) {
        char* p = ws + off;
        off += (bytes + 255) & ~(size_t)255;
        return p;
    };

    unsigned short* W1t = (unsigned short*)alloc((size_t)HID * KP * 2);  // [1024][10048]
    unsigned short* W2t = (unsigned short*)alloc((size_t)EMB * HID * 2); // [128][1024]
    float* P = (float*)alloc((size_t)NB * EMB * 4);
    float* Q = (float*)alloc((size_t)NB * EMB * 4);

    size_t rem = (ws_size > off) ? (ws_size - off) : 0;
    const size_t perRow = (size_t)KP * 2 + (size_t)HID * 2;  // 22144 B / batch row
    int mc = (int)(rem / perRow);
    mc = (mc / 128) * 128;
    if (mc > NB) mc = NB;
    if (mc < 128) mc = 128;
    unsigned short* Abf = (unsigned short*)alloc((size_t)mc * KP * 2);
    unsigned short* H1  = (unsigned short*)alloc((size_t)mc * HID * 2);

    dim3 blk(256);
    for (int side = 0; side < 2; ++side) {
        const float* X  = side ? item : user;
        const float* W1 = side ? Wi1 : Wu1;
        const float* b1 = side ? bi1 : bu1;
        const float* W2 = side ? Wi2 : Wu2;
        const float* b2 = side ? bi2 : bu2;
        float* PQ = side ? Q : P;

        conv_transpose<<<dim3(KP / 64, HID / 32), blk, 0, stream>>>(W1, W1t, DIN, HID, KP);
        conv_transpose<<<dim3(HID / 64, EMB / 32), blk, 0, stream>>>(W2, W2t, HID, EMB, HID);

        for (int m0 = 0; m0 < NB; m0 += mc) {
            int rows = (mc < NB - m0) ? mc : (NB - m0);
            conv_pad<<<dim3((KP / 4 + 255) / 256, rows), blk, 0, stream>>>(
                X + (size_t)m0 * DIN, Abf);
            dim3 g1(HID / 128, rows / 128);
            gemm_rt_bt<true, true, true><<<g1, blk, 0, stream>>>(
                Abf, W1t, b1, H1, KP, KP, HID, KP / 32);
            dim3 g2(EMB / 128, rows / 128);
            gemm_rt_bt<false, false, false><<<g2, blk, 0, stream>>>(
                H1, W2t, b2, PQ + (size_t)m0 * EMB, HID, HID, EMB, HID / 32);
        }
    }
    rowdot<<<(NB * 64) / 256, blk, 0, stream>>>(P, Q, out, NB);
}